// Round 16
// baseline (152.105 us; speedup 1.0000x reference)
//
#include <hip/hip_runtime.h>
#include <hip/hip_bf16.h>

typedef __attribute__((ext_vector_type(8))) short short8;
typedef __attribute__((ext_vector_type(4))) float f32x4;

__device__ __forceinline__ unsigned short f2bf(float f) {
  union { float f; unsigned int u; } x; x.f = f;
  unsigned int r = x.u + 0x7fffu + ((x.u >> 16) & 1u);
  return (unsigned short)(r >> 16);
}

// Raw hardware exp2 (single v_exp_f32) — round-11 proven (+9.6 us on attn).
__device__ __forceinline__ float fexp2(float x) {
#if __has_builtin(__builtin_amdgcn_exp2f)
  return __builtin_amdgcn_exp2f(x);
#else
  float r;
  asm("v_exp_f32 %0, %1" : "=v"(r) : "v"(x));
  return r;
#endif
}

#define MFMA16(a, b, c) __builtin_amdgcn_mfma_f32_16x16x32_bf16((a), (b), (c), 0, 0, 0)

__device__ __forceinline__ void gload_lds16(const void* g, void* l) {
  __builtin_amdgcn_global_load_lds((const __attribute__((address_space(1))) void*)g,
                                   (__attribute__((address_space(3))) void*)l, 16, 0, 0);
}

#define WAIT_VM(n) asm volatile("s_waitcnt vmcnt(" #n ")" ::: "memory")
#define RAW_BAR() asm volatile("s_barrier" ::: "memory")

// D,S distinct-value pair swaps (operands must hold DIFFERENT values so the
// register allocator cannot coalesce them — round-9 lesson).
__device__ __forceinline__ void p32swap(unsigned int& a, unsigned int& b) {
  asm volatile("v_permlane32_swap_b32 %0, %1" : "+v"(a), "+v"(b));
}
__device__ __forceinline__ void p16swap(unsigned int& a, unsigned int& b) {
  asm volatile("v_permlane16_swap_b32 %0, %1" : "+v"(a), "+v"(b));
}

// 0.125 (HEAD_DIM^-0.5) * log2(e): folded so attention can use exp2 directly.
#define QSCALE 0.1803368801111244f

// Fused f32->bf16 conversion for q,k,v and the four weights in ONE launch.
__global__ __launch_bounds__(256) void cvt_all(
    const float* __restrict__ q, const float* __restrict__ k,
    const float* __restrict__ v, const float* __restrict__ w0,
    const float* __restrict__ w1, const float* __restrict__ w2,
    const float* __restrict__ w3, unsigned short* __restrict__ Tb,
    unsigned short* __restrict__ Kc, unsigned short* __restrict__ Vc,
    unsigned short* __restrict__ Wb) {
  const int lin = blockIdx.x;
  const float* src;
  unsigned short* dst;
  int i0;
  if (lin < 4096)        { src = q;  dst = Tb;                i0 = lin; }
  else if (lin < 8192)   { src = k;  dst = Kc;                i0 = lin - 4096; }
  else if (lin < 12288)  { src = v;  dst = Vc;                i0 = lin - 8192; }
  else if (lin < 12800)  { src = w0; dst = Wb;                i0 = lin - 12288; }
  else if (lin < 13312)  { src = w1; dst = Wb + (1u << 20);   i0 = lin - 12800; }
  else if (lin < 13824)  { src = w2; dst = Wb + (2u << 20);   i0 = lin - 13312; }
  else                   { src = w3; dst = Wb + (3u << 20);   i0 = lin - 13824; }
  const size_t i = (size_t)i0 * 256 + threadIdx.x;
  const float4* p = (const float4*)src + 2 * i;
  float4 a = p[0], b = p[1];
  ushort4 lo, hi;
  lo.x = f2bf(a.x); lo.y = f2bf(a.y); lo.z = f2bf(a.z); lo.w = f2bf(a.w);
  hi.x = f2bf(b.x); hi.y = f2bf(b.y); hi.z = f2bf(b.z); hi.w = f2bf(b.w);
  ((ushort4*)dst)[2 * i] = lo;
  ((ushort4*)dst)[2 * i + 1] = hi;
}

// Shared GEMM core: C[m,n] = sum_k A[m,k]*W[n,k]; 128x128 tile, 8 waves,
// dbuf 2-phase counted-vmcnt, LDS XOR-swizzled, grid.x = bm (XCD = bm%8).
template <bool SWAP>
__device__ __forceinline__ void gemm_core(const unsigned short* __restrict__ A,
                                          const unsigned short* __restrict__ W,
                                          unsigned short (*As)[128 * 64],
                                          unsigned short (*Bs)[128 * 64],
                                          int bm, int bn, f32x4 (&acc)[2][4]) {
  const int tid = threadIdx.x, lane = tid & 63, wid = tid >> 6;
  const int g = lane >> 4, li = lane & 15;
  const int wr = wid >> 1, wc = wid & 1;
  const int trow = tid >> 3;
  const int js = (tid & 7) ^ (trow & 7);

  auto stage = [&](int kt, int pb) {
    const int k0 = kt << 6;
    #pragma unroll
    for (int r = 0; r < 2; ++r) {
      const int row = r * 64 + trow;
      gload_lds16(A + (size_t)(bm * 128 + row) * 1024 + k0 + js * 8,
                  &As[pb][(r * 64 + wid * 8) * 64]);
      gload_lds16(W + (size_t)(bn * 128 + row) * 1024 + k0 + js * 8,
                  &Bs[pb][(r * 64 + wid * 8) * 64]);
    }
  };

  stage(0, 0);
  int p = 0;
  for (int kt = 0; kt < 16; ++kt) {
    if (kt < 15) {
      stage(kt + 1, p ^ 1);
      WAIT_VM(4);
    } else {
      WAIT_VM(0);
    }
    RAW_BAR();
    #pragma unroll
    for (int kst = 0; kst < 2; ++kst) {
      short8 a[2], b[4];
      #pragma unroll
      for (int mi = 0; mi < 2; ++mi) {
        const int row = wr * 32 + mi * 16 + li;
        a[mi] = *(const short8*)((const char*)&As[p][0] + row * 128 +
                                 (((kst * 4 + g) ^ (li & 7)) << 4));
      }
      #pragma unroll
      for (int ni = 0; ni < 4; ++ni) {
        const int row = wc * 64 + ni * 16 + li;
        b[ni] = *(const short8*)((const char*)&Bs[p][0] + row * 128 +
                                 (((kst * 4 + g) ^ (li & 7)) << 4));
      }
      __builtin_amdgcn_s_setprio(1);
      #pragma unroll
      for (int mi = 0; mi < 2; ++mi)
        #pragma unroll
        for (int ni = 0; ni < 4; ++ni) {
          if constexpr (SWAP)
            acc[mi][ni] = MFMA16(b[ni], a[mi], acc[mi][ni]);
          else
            acc[mi][ni] = MFMA16(a[mi], b[ni], acc[mi][ni]);
        }
      __builtin_amdgcn_s_setprio(0);
    }
    RAW_BAR();
    p ^= 1;
  }
}

// Fused Q/K/V projection: grid (64 bm, 8 bn, 3 z). One launch, no inter-GEMM
// drain (round-15 proven). z=0: Q (scaled); z=1: K; z=2: Vt (transposed).
__global__ __launch_bounds__(512) void qkv_gemm(
    const unsigned short* __restrict__ Aq, const unsigned short* __restrict__ Ak,
    const unsigned short* __restrict__ Av, const unsigned short* __restrict__ Wb,
    const float* __restrict__ bq, const float* __restrict__ bk,
    const float* __restrict__ bv, unsigned short* __restrict__ Qw,
    unsigned short* __restrict__ Kw, unsigned short* __restrict__ Vw) {
  __shared__ unsigned short As[2][128 * 64];
  __shared__ unsigned short Bs[2][128 * 64];
  const int z = blockIdx.z;
  const int bm = blockIdx.x, bn = blockIdx.y;
  const unsigned short* A = (z == 0) ? Aq : (z == 1) ? Ak : Av;
  const unsigned short* W = Wb + ((size_t)z << 20);
  const float* bias = (z == 0) ? bq : (z == 1) ? bk : bv;
  unsigned short* outp = (z == 0) ? Qw : (z == 1) ? Kw : Vw;

  const int tid = threadIdx.x, lane = tid & 63, wid = tid >> 6;
  const int g = lane >> 4, li = lane & 15;
  const int wr = wid >> 1, wc = wid & 1;

  f32x4 acc[2][4] = {};
  if (z == 2)
    gemm_core<true>(A, W, As, Bs, bm, bn, acc);
  else
    gemm_core<false>(A, W, As, Bs, bm, bn, acc);

  if (z == 2) {
    #pragma unroll
    for (int mi = 0; mi < 2; ++mi) {
      const int mm = bm * 128 + wr * 32 + mi * 16 + li;
      const int b_ = mm >> 12, t_ = mm & 4095;
      #pragma unroll
      for (int ni = 0; ni < 4; ++ni)
        #pragma unroll
        for (int r = 0; r < 4; ++r) {
          const int nn = bn * 128 + wc * 64 + ni * 16 + g * 4 + r;
          const int h_ = nn >> 6, d_ = nn & 63;
          float v = acc[mi][ni][r] + bias[nn];
          outp[(((size_t)(b_ * 16 + h_) * 64 + d_) << 12) + t_] = f2bf(v);
        }
    }
  } else {
    const float scale = (z == 0) ? QSCALE : 1.0f;
    #pragma unroll
    for (int mi = 0; mi < 2; ++mi)
      #pragma unroll
      for (int ni = 0; ni < 4; ++ni) {
        const int nn = bn * 128 + wc * 64 + ni * 16 + li;
        const float bv_ = bias[nn];
        #pragma unroll
        for (int r = 0; r < 4; ++r) {
          const int mm = bm * 128 + wr * 32 + mi * 16 + g * 4 + r;
          const float v = (acc[mi][ni][r] + bv_) * scale;
          const int b_ = mm >> 12, t_ = mm & 4095, h_ = nn >> 6, d_ = nn & 63;
          outp[(((size_t)(b_ * 16 + h_) * 4096 + t_) << 6) + d_] = f2bf(v);
        }
      }
  }
}

// Output projection (f32 out + bias).
__global__ __launch_bounds__(512) void out_gemm(const unsigned short* __restrict__ A,
                                                const unsigned short* __restrict__ W,
                                                const float* __restrict__ bias,
                                                float* __restrict__ outp) {
  __shared__ unsigned short As[2][128 * 64];
  __shared__ unsigned short Bs[2][128 * 64];
  const int bm = blockIdx.x, bn = blockIdx.y;
  const int tid = threadIdx.x, lane = tid & 63, wid = tid >> 6;
  const int g = lane >> 4, li = lane & 15;
  const int wr = wid >> 1, wc = wid & 1;
  f32x4 acc[2][4] = {};
  gemm_core<false>(A, W, As, Bs, bm, bn, acc);
  #pragma unroll
  for (int mi = 0; mi < 2; ++mi)
    #pragma unroll
    for (int ni = 0; ni < 4; ++ni) {
      const int nn = bn * 128 + wc * 64 + ni * 16 + li;
      const float bv_ = bias[nn];
      #pragma unroll
      for (int r = 0; r < 4; ++r) {
        const int mm = bm * 128 + wr * 32 + mi * 16 + g * 4 + r;
        outp[(size_t)mm * 1024 + nn] = acc[mi][ni][r] + bv_;
      }
    }
}

// Sliding-window attention, TRIPLE-buffered / ONE barrier per chunk (round-16).
// Per iteration: {waitvm; barrier; stage(c+2)->buf[(c+2)%3]; compute(buf[c%3])}.
// RAW: vmcnt(4) drains exactly chunk c (FIFO; c+1's 4 loads stay in flight).
// WAR: stage(c+2) overwrites buf[(c-1)%3]; the iteration-c barrier post-dates
// every wave's compute(c-1) (program order), whose lgkm waits consumed the
// reads. Buffers within an interval are disjoint ((c+2)%3 != c%3).
// Barriers per chunk 2->1; each staged chunk now has TWO compute intervals
// to land. XCD-group block decode (round-13), XOR-swizzle, in-register P
// redistribution, ones-MFMA row-sum, no-max softmax, raw v_exp_f32.
__global__ __launch_bounds__(256) void swa_attn(const unsigned short* __restrict__ Q,
                                                const unsigned short* __restrict__ K,
                                                const unsigned short* __restrict__ V,
                                                unsigned short* __restrict__ O) {
  __shared__ unsigned short Kb[3][4096];      // [64 keys][64 d], swizzled
  __shared__ unsigned short Vb[3][4096];      // [64 d][64 keys], swizzled
  const int tid = threadIdx.x, lane = tid & 63, w = tid >> 6;
  const int g = lane >> 4, li = lane & 15;
  const int lin = blockIdx.x;
  const int xcd = lin & 7;
  const int rest = lin >> 3;
  const int qoff = rest & 7;
  const int grp = rest >> 3;
  const int G = xcd * 16 + grp;
  const int hb = G & 31;
  const int qb = (G >> 5) * 8 + qoff;
  const int qs = qb << 7;
  const int h = hb & 15, b = hb >> 4;
  const int bh = b * 16 + h;
  const unsigned short* Qh = Q + ((size_t)bh << 18);
  const unsigned short* Kh = K + ((size_t)bh << 18);
  const unsigned short* Vh = V + ((size_t)bh << 18);

  short8 qa[2][2];
  #pragma unroll
  for (int qt = 0; qt < 2; ++qt)
    #pragma unroll
    for (int kst = 0; kst < 2; ++kst)
      qa[qt][kst] =
          *(const short8*)&Qh[((size_t)(qs + w * 32 + qt * 16 + li) << 6) + kst * 32 + g * 8];

  const short8 vone = {0x3F80, 0x3F80, 0x3F80, 0x3F80, 0x3F80, 0x3F80, 0x3F80, 0x3F80};
  f32x4 o[2][4] = {};
  f32x4 lac[2] = {};
  const int c0 = (qs >= 512) ? 0 : ((512 - qs) >> 6);

  const int srow_hi = lane >> 3;
  const int sj = lane & 7;

  auto stage = [&](int c, int pb) {
    const int ks = qs - 512 + (c << 6);
    #pragma unroll
    for (int i = 0; i < 2; ++i) {
      const int seg = w + i * 4;
      const int row = seg * 8 + srow_hi;
      const int jsw = sj ^ (row & 7);
      gload_lds16(Kh + (((size_t)(ks + row)) << 6) + jsw * 8, &Kb[pb][seg * 512]);
      gload_lds16(Vh + (((size_t)row) << 12) + ks + jsw * 8, &Vb[pb][seg * 512]);
    }
  };

  stage(c0, c0 % 3);
  stage(c0 + 1, (c0 + 1) % 3);   // c0 <= 8, so c0+1 <= 9 always valid

  for (int c = c0; c <= 9; ++c) {
    if (c < 9) {
      WAIT_VM(4);      // chunk c's 4 loads done; chunk c+1's 4 in flight
    } else {
      WAIT_VM(0);
    }
    RAW_BAR();
    if (c + 2 <= 9) stage(c + 2, (c + 2) % 3);
    const int p = c % 3;
    const int cb = c << 6;
    const bool anyq = (cb + 63 >= w * 32) && (cb <= w * 32 + 543);
    if (anyq) {
      short8 kf[4][2], vf[4][2];
      #pragma unroll
      for (int nt = 0; nt < 4; ++nt) {
        const int row = nt * 16 + li, rx = li & 7;
        #pragma unroll
        for (int kst = 0; kst < 2; ++kst) {
          const int byt = row * 128 + (((kst * 4 + g) ^ rx) << 4);
          kf[nt][kst] = *(const short8*)((const char*)&Kb[p][0] + byt);
          vf[nt][kst] = *(const short8*)((const char*)&Vb[p][0] + byt);
        }
      }
      #pragma unroll
      for (int qt = 0; qt < 2; ++qt) {
        const int base = w * 32 + qt * 16;
        if (cb + 63 < base || cb > base + 527) continue;
        f32x4 s[4];
        __builtin_amdgcn_s_setprio(1);
        #pragma unroll
        for (int nt = 0; nt < 4; ++nt) {
          f32x4 z = {};
          s[nt] = MFMA16(kf[nt][0], qa[qt][0], z);
          s[nt] = MFMA16(kf[nt][1], qa[qt][1], s[nt]);
        }
        __builtin_amdgcn_s_setprio(0);
        if (cb < base + 16 || cb + 63 > base + 512) {
          #pragma unroll
          for (int nt = 0; nt < 4; ++nt)
            #pragma unroll
            for (int r = 0; r < 4; ++r) {
              const int t1 = cb + nt * 16 + g * 4 + r - base;
              if (t1 < li || t1 > 512 + li) s[nt][r] = -3e38f;
            }
        }
        unsigned int pw[4][2];
        #pragma unroll
        for (int nt = 0; nt < 4; ++nt) {
          float2 ab; ab.x = fexp2(s[nt][0]); ab.y = fexp2(s[nt][1]);
          float2 cd; cd.x = fexp2(s[nt][2]); cd.y = fexp2(s[nt][3]);
          union { __hip_bfloat162 h2; unsigned int u; } u0, u1;
          u0.h2 = __float22bfloat162_rn(ab);
          u1.h2 = __float22bfloat162_rn(cd);
          pw[nt][0] = u0.u;
          pw[nt][1] = u1.u;
        }
        short8 pbf[2];
        #pragma unroll
        for (int kst = 0; kst < 2; ++kst) {
          unsigned int A0 = pw[2 * kst][0], B0 = pw[2 * kst + 1][0];
          unsigned int A1 = pw[2 * kst][1], B1 = pw[2 * kst + 1][1];
          p32swap(A0, B0);
          p32swap(A1, B1);
          p16swap(A0, B0);
          p16swap(A1, B1);
          union { unsigned int u[4]; short8 s8; } pb_;
          pb_.u[0] = A0;
          pb_.u[1] = A1;
          pb_.u[2] = B0;
          pb_.u[3] = B1;
          pbf[kst] = pb_.s8;
        }
        __builtin_amdgcn_s_setprio(1);
        lac[qt] = MFMA16(vone, pbf[0], lac[qt]);
        lac[qt] = MFMA16(vone, pbf[1], lac[qt]);
        #pragma unroll
        for (int dt = 0; dt < 4; ++dt) {
          o[qt][dt] = MFMA16(vf[dt][0], pbf[0], o[qt][dt]);
          o[qt][dt] = MFMA16(vf[dt][1], pbf[1], o[qt][dt]);
        }
        __builtin_amdgcn_s_setprio(0);
      }
    }
  }

  #pragma unroll
  for (int qt = 0; qt < 2; ++qt) {
    const float inv = 1.0f / lac[qt][0];
    const int t_ = qs + w * 32 + qt * 16 + li;
    #pragma unroll
    for (int dt = 0; dt < 4; ++dt) {
      ushort4 u;
      u.x = f2bf(o[qt][dt][0] * inv); u.y = f2bf(o[qt][dt][1] * inv);
      u.z = f2bf(o[qt][dt][2] * inv); u.w = f2bf(o[qt][dt][3] * inv);
      *(ushort4*)&O[((size_t)(b * 4096 + t_) << 10) + h * 64 + dt * 16 + g * 4] = u;
    }
  }
}

extern "C" void kernel_launch(void* const* d_in, const int* in_sizes, int n_in,
                              void* d_out, int out_size, void* d_ws, size_t ws_size,
                              hipStream_t stream) {
  const float* q_in = (const float*)d_in[0];
  const float* k_in = (const float*)d_in[1];
  const float* v_in = (const float*)d_in[2];
  const float* wq = (const float*)d_in[3];
  const float* bq = (const float*)d_in[4];
  const float* wk = (const float*)d_in[5];
  const float* bk = (const float*)d_in[6];
  const float* wv = (const float*)d_in[7];
  const float* bv = (const float*)d_in[8];
  const float* wo = (const float*)d_in[9];
  const float* bo = (const float*)d_in[10];

  unsigned short* Qw = (unsigned short*)d_ws;   // [2*16][4096][64] bf16 (pre-scaled)
  unsigned short* Kw = Qw + (size_t)8388608;    // [2*16][4096][64]
  unsigned short* Vw = Kw + (size_t)8388608;    // [2*16][64][4096]
  unsigned short* Tb = Vw + (size_t)8388608;    // q-staging, then attn out
  unsigned short* Wb = Tb + (size_t)8388608;    // weights bf16 [4][1024][1024]
  // k/v bf16 staging in d_out (16M shorts), overwritten by out_gemm.
  unsigned short* Kc = (unsigned short*)d_out;
  unsigned short* Vc = Kc + (size_t)8388608;

  dim3 bb(256), bg(512);
  cvt_all<<<14336, bb, 0, stream>>>(q_in, k_in, v_in, wq, wk, wv, wo,
                                    Tb, Kc, Vc, Wb);
  qkv_gemm<<<dim3(64, 8, 3), bg, 0, stream>>>(Tb, Kc, Vc, Wb, bq, bk, bv,
                                              Qw, Kw, Vw);
  swa_attn<<<1024, bb, 0, stream>>>(Qw, Kw, Vw, Tb);
  out_gemm<<<dim3(64, 8), bg, 0, stream>>>(Tb, Wb + (3u << 20), bo,
                                           (float*)d_out);
}

// Round 17
// 149.955 us; speedup vs baseline: 1.0143x; 1.0143x over previous
//
#include <hip/hip_runtime.h>
#include <hip/hip_bf16.h>

typedef __attribute__((ext_vector_type(8))) short short8;
typedef __attribute__((ext_vector_type(4))) float f32x4;

__device__ __forceinline__ unsigned short f2bf(float f) {
  union { float f; unsigned int u; } x; x.f = f;
  unsigned int r = x.u + 0x7fffu + ((x.u >> 16) & 1u);
  return (unsigned short)(r >> 16);
}

// Raw hardware exp2 (single v_exp_f32) — round-11 proven (+9.6 us on attn).
__device__ __forceinline__ float fexp2(float x) {
#if __has_builtin(__builtin_amdgcn_exp2f)
  return __builtin_amdgcn_exp2f(x);
#else
  float r;
  asm("v_exp_f32 %0, %1" : "=v"(r) : "v"(x));
  return r;
#endif
}

#define MFMA16(a, b, c) __builtin_amdgcn_mfma_f32_16x16x32_bf16((a), (b), (c), 0, 0, 0)

__device__ __forceinline__ void gload_lds16(const void* g, void* l) {
  __builtin_amdgcn_global_load_lds((const __attribute__((address_space(1))) void*)g,
                                   (__attribute__((address_space(3))) void*)l, 16, 0, 0);
}

#define WAIT_VM(n) asm volatile("s_waitcnt vmcnt(" #n ")" ::: "memory")
#define RAW_BAR() asm volatile("s_barrier" ::: "memory")

// D,S distinct-value pair swaps (operands must hold DIFFERENT values so the
// register allocator cannot coalesce them — round-9 lesson).
__device__ __forceinline__ void p32swap(unsigned int& a, unsigned int& b) {
  asm volatile("v_permlane32_swap_b32 %0, %1" : "+v"(a), "+v"(b));
}
__device__ __forceinline__ void p16swap(unsigned int& a, unsigned int& b) {
  asm volatile("v_permlane16_swap_b32 %0, %1" : "+v"(a), "+v"(b));
}

// 0.125 (HEAD_DIM^-0.5) * log2(e): folded so attention can use exp2 directly.
#define QSCALE 0.1803368801111244f

// Fused f32->bf16 conversion for q,k,v and the four weights in ONE launch.
__global__ __launch_bounds__(256) void cvt_all(
    const float* __restrict__ q, const float* __restrict__ k,
    const float* __restrict__ v, const float* __restrict__ w0,
    const float* __restrict__ w1, const float* __restrict__ w2,
    const float* __restrict__ w3, unsigned short* __restrict__ Tb,
    unsigned short* __restrict__ Kc, unsigned short* __restrict__ Vc,
    unsigned short* __restrict__ Wb) {
  const int lin = blockIdx.x;
  const float* src;
  unsigned short* dst;
  int i0;
  if (lin < 4096)        { src = q;  dst = Tb;                i0 = lin; }
  else if (lin < 8192)   { src = k;  dst = Kc;                i0 = lin - 4096; }
  else if (lin < 12288)  { src = v;  dst = Vc;                i0 = lin - 8192; }
  else if (lin < 12800)  { src = w0; dst = Wb;                i0 = lin - 12288; }
  else if (lin < 13312)  { src = w1; dst = Wb + (1u << 20);   i0 = lin - 12800; }
  else if (lin < 13824)  { src = w2; dst = Wb + (2u << 20);   i0 = lin - 13312; }
  else                   { src = w3; dst = Wb + (3u << 20);   i0 = lin - 13824; }
  const size_t i = (size_t)i0 * 256 + threadIdx.x;
  const float4* p = (const float4*)src + 2 * i;
  float4 a = p[0], b = p[1];
  ushort4 lo, hi;
  lo.x = f2bf(a.x); lo.y = f2bf(a.y); lo.z = f2bf(a.z); lo.w = f2bf(a.w);
  hi.x = f2bf(b.x); hi.y = f2bf(b.y); hi.z = f2bf(b.z); hi.w = f2bf(b.w);
  ((ushort4*)dst)[2 * i] = lo;
  ((ushort4*)dst)[2 * i + 1] = hi;
}

// Shared GEMM core: C[m,n] = sum_k A[m,k]*W[n,k]; 128x128 tile, 8 waves,
// dbuf 2-phase counted-vmcnt, LDS XOR-swizzled, grid.x = bm (XCD = bm%8).
template <bool SWAP>
__device__ __forceinline__ void gemm_core(const unsigned short* __restrict__ A,
                                          const unsigned short* __restrict__ W,
                                          unsigned short (*As)[128 * 64],
                                          unsigned short (*Bs)[128 * 64],
                                          int bm, int bn, f32x4 (&acc)[2][4]) {
  const int tid = threadIdx.x, lane = tid & 63, wid = tid >> 6;
  const int g = lane >> 4, li = lane & 15;
  const int wr = wid >> 1, wc = wid & 1;
  const int trow = tid >> 3;
  const int js = (tid & 7) ^ (trow & 7);

  auto stage = [&](int kt, int pb) {
    const int k0 = kt << 6;
    #pragma unroll
    for (int r = 0; r < 2; ++r) {
      const int row = r * 64 + trow;
      gload_lds16(A + (size_t)(bm * 128 + row) * 1024 + k0 + js * 8,
                  &As[pb][(r * 64 + wid * 8) * 64]);
      gload_lds16(W + (size_t)(bn * 128 + row) * 1024 + k0 + js * 8,
                  &Bs[pb][(r * 64 + wid * 8) * 64]);
    }
  };

  stage(0, 0);
  int p = 0;
  for (int kt = 0; kt < 16; ++kt) {
    if (kt < 15) {
      stage(kt + 1, p ^ 1);
      WAIT_VM(4);
    } else {
      WAIT_VM(0);
    }
    RAW_BAR();
    #pragma unroll
    for (int kst = 0; kst < 2; ++kst) {
      short8 a[2], b[4];
      #pragma unroll
      for (int mi = 0; mi < 2; ++mi) {
        const int row = wr * 32 + mi * 16 + li;
        a[mi] = *(const short8*)((const char*)&As[p][0] + row * 128 +
                                 (((kst * 4 + g) ^ (li & 7)) << 4));
      }
      #pragma unroll
      for (int ni = 0; ni < 4; ++ni) {
        const int row = wc * 64 + ni * 16 + li;
        b[ni] = *(const short8*)((const char*)&Bs[p][0] + row * 128 +
                                 (((kst * 4 + g) ^ (li & 7)) << 4));
      }
      __builtin_amdgcn_s_setprio(1);
      #pragma unroll
      for (int mi = 0; mi < 2; ++mi)
        #pragma unroll
        for (int ni = 0; ni < 4; ++ni) {
          if constexpr (SWAP)
            acc[mi][ni] = MFMA16(b[ni], a[mi], acc[mi][ni]);
          else
            acc[mi][ni] = MFMA16(a[mi], b[ni], acc[mi][ni]);
        }
      __builtin_amdgcn_s_setprio(0);
    }
    RAW_BAR();
    p ^= 1;
  }
}

// Fused Q/K/V projection: grid (64 bm, 8 bn, 3 z). One launch (round-15).
__global__ __launch_bounds__(512) void qkv_gemm(
    const unsigned short* __restrict__ Aq, const unsigned short* __restrict__ Ak,
    const unsigned short* __restrict__ Av, const unsigned short* __restrict__ Wb,
    const float* __restrict__ bq, const float* __restrict__ bk,
    const float* __restrict__ bv, unsigned short* __restrict__ Qw,
    unsigned short* __restrict__ Kw, unsigned short* __restrict__ Vw) {
  __shared__ unsigned short As[2][128 * 64];
  __shared__ unsigned short Bs[2][128 * 64];
  const int z = blockIdx.z;
  const int bm = blockIdx.x, bn = blockIdx.y;
  const unsigned short* A = (z == 0) ? Aq : (z == 1) ? Ak : Av;
  const unsigned short* W = Wb + ((size_t)z << 20);
  const float* bias = (z == 0) ? bq : (z == 1) ? bk : bv;
  unsigned short* outp = (z == 0) ? Qw : (z == 1) ? Kw : Vw;

  const int tid = threadIdx.x, lane = tid & 63, wid = tid >> 6;
  const int g = lane >> 4, li = lane & 15;
  const int wr = wid >> 1, wc = wid & 1;

  f32x4 acc[2][4] = {};
  if (z == 2)
    gemm_core<true>(A, W, As, Bs, bm, bn, acc);
  else
    gemm_core<false>(A, W, As, Bs, bm, bn, acc);

  if (z == 2) {
    #pragma unroll
    for (int mi = 0; mi < 2; ++mi) {
      const int mm = bm * 128 + wr * 32 + mi * 16 + li;
      const int b_ = mm >> 12, t_ = mm & 4095;
      #pragma unroll
      for (int ni = 0; ni < 4; ++ni)
        #pragma unroll
        for (int r = 0; r < 4; ++r) {
          const int nn = bn * 128 + wc * 64 + ni * 16 + g * 4 + r;
          const int h_ = nn >> 6, d_ = nn & 63;
          float v = acc[mi][ni][r] + bias[nn];
          outp[(((size_t)(b_ * 16 + h_) * 64 + d_) << 12) + t_] = f2bf(v);
        }
    }
  } else {
    const float scale = (z == 0) ? QSCALE : 1.0f;
    #pragma unroll
    for (int mi = 0; mi < 2; ++mi)
      #pragma unroll
      for (int ni = 0; ni < 4; ++ni) {
        const int nn = bn * 128 + wc * 64 + ni * 16 + li;
        const float bv_ = bias[nn];
        #pragma unroll
        for (int r = 0; r < 4; ++r) {
          const int mm = bm * 128 + wr * 32 + mi * 16 + g * 4 + r;
          const float v = (acc[mi][ni][r] + bv_) * scale;
          const int b_ = mm >> 12, t_ = mm & 4095, h_ = nn >> 6, d_ = nn & 63;
          outp[(((size_t)(b_ * 16 + h_) * 4096 + t_) << 6) + d_] = f2bf(v);
        }
      }
  }
}

// Output projection (f32 out + bias).
__global__ __launch_bounds__(512) void out_gemm(const unsigned short* __restrict__ A,
                                                const unsigned short* __restrict__ W,
                                                const float* __restrict__ bias,
                                                float* __restrict__ outp) {
  __shared__ unsigned short As[2][128 * 64];
  __shared__ unsigned short Bs[2][128 * 64];
  const int bm = blockIdx.x, bn = blockIdx.y;
  const int tid = threadIdx.x, lane = tid & 63, wid = tid >> 6;
  const int g = lane >> 4, li = lane & 15;
  const int wr = wid >> 1, wc = wid & 1;
  f32x4 acc[2][4] = {};
  gemm_core<false>(A, W, As, Bs, bm, bn, acc);
  #pragma unroll
  for (int mi = 0; mi < 2; ++mi)
    #pragma unroll
    for (int ni = 0; ni < 4; ++ni) {
      const int nn = bn * 128 + wc * 64 + ni * 16 + li;
      const float bv_ = bias[nn];
      #pragma unroll
      for (int r = 0; r < 4; ++r) {
        const int mm = bm * 128 + wr * 32 + mi * 16 + g * 4 + r;
        outp[(size_t)mm * 1024 + nn] = acc[mi][ni][r] + bv_;
      }
    }
}

// Sliding-window attention, 8-wave Q256 block + 128-key pair staging (r17).
// 512 threads stage a PAIR of 64-key chunks (K+V = 32KB, 4 loads/thread) per
// barrier interval; all 8 waves consume it (staging/barriers per wave halved
// vs Q128; 2 chunk-computes per interval). Inner chunk compute identical to
// the round-13-proven code. XCD-group decode over 512 blocks (qb 0..15).
__global__ __launch_bounds__(512) void swa_attn(const unsigned short* __restrict__ Q,
                                                const unsigned short* __restrict__ K,
                                                const unsigned short* __restrict__ V,
                                                unsigned short* __restrict__ O) {
  __shared__ unsigned short Kb[2][8192];   // pair: [128 keys][64 d], swizzled
  __shared__ unsigned short Vb[2][8192];   // pair: 2x [64 d][64 keys], swizzled
  const int tid = threadIdx.x, lane = tid & 63, w = tid >> 6;
  const int g = lane >> 4, li = lane & 15;
  const int lin = blockIdx.x;
  const int xcd = lin & 7;
  const int rest = lin >> 3;        // [0,64)
  const int qoff = rest & 7;        // 8 consecutive qb per group
  const int grp = rest >> 3;        // [0,8) groups per XCD
  const int G = xcd * 8 + grp;      // [0,64)
  const int hb = G & 31;
  const int qb = (G >> 5) * 8 + qoff;  // [0,16)
  const int qs = qb << 8;
  const int h = hb & 15, b = hb >> 4;
  const int bh = b * 16 + h;
  const unsigned short* Qh = Q + ((size_t)bh << 18);
  const unsigned short* Kh = K + ((size_t)bh << 18);
  const unsigned short* Vh = V + ((size_t)bh << 18);

  short8 qa[2][2];
  #pragma unroll
  for (int qt = 0; qt < 2; ++qt)
    #pragma unroll
    for (int kst = 0; kst < 2; ++kst)
      qa[qt][kst] =
          *(const short8*)&Qh[((size_t)(qs + w * 32 + qt * 16 + li) << 6) + kst * 32 + g * 8];

  const short8 vone = {0x3F80, 0x3F80, 0x3F80, 0x3F80, 0x3F80, 0x3F80, 0x3F80, 0x3F80};
  f32x4 o[2][4] = {};
  f32x4 lac[2] = {};
  // c0 in {8,4,0} (qs multiple of 256) -> always even; pair index p0 = c0/2.
  const int c0 = (qs >= 512) ? 0 : ((512 - qs) >> 6);
  const int p0 = c0 >> 1;

  const int srow_hi = lane >> 3;   // 0..7
  const int sj = lane & 7;

  // stage one PAIR of chunks (128 keys): 4 loads/thread (K,V x 2 sub-chunks).
  auto stage = [&](int pi, int pb) {
    const int ks0 = qs - 512 + (pi << 7);
    #pragma unroll
    for (int s = 0; s < 2; ++s) {
      const int row = w * 8 + srow_hi;            // 0..63 within sub-chunk
      const int jsw = sj ^ (row & 7);
      gload_lds16(Kh + (((size_t)(ks0 + s * 64 + row)) << 6) + jsw * 8,
                  &Kb[pb][s * 4096 + w * 512]);
      gload_lds16(Vh + (((size_t)row) << 12) + ks0 + s * 64 + jsw * 8,
                  &Vb[pb][s * 4096 + w * 512]);
    }
  };

  int pb = 0;
  stage(p0, 0);

  for (int pi = p0; pi <= 5; ++pi) {
    if (pi < 5) {
      stage(pi + 1, pb ^ 1);
      WAIT_VM(4);      // this pair's 4 loads done; next pair's in flight
    } else {
      WAIT_VM(0);
    }
    RAW_BAR();
    #pragma unroll
    for (int s = 0; s < 2; ++s) {
      const int c = 2 * pi + s;
      const int cb = c << 6;
      const bool anyq = (cb + 63 >= w * 32) && (cb <= w * 32 + 543);
      if (anyq) {
        short8 kf[4][2], vf[4][2];
        #pragma unroll
        for (int nt = 0; nt < 4; ++nt) {
          const int row = nt * 16 + li, rx = li & 7;
          #pragma unroll
          for (int kst = 0; kst < 2; ++kst) {
            const int byt = s * 8192 + row * 128 + (((kst * 4 + g) ^ rx) << 4);
            kf[nt][kst] = *(const short8*)((const char*)&Kb[pb][0] + byt);
            vf[nt][kst] = *(const short8*)((const char*)&Vb[pb][0] + byt);
          }
        }
        #pragma unroll
        for (int qt = 0; qt < 2; ++qt) {
          const int base = w * 32 + qt * 16;
          if (cb + 63 < base || cb > base + 527) continue;
          f32x4 sv[4];
          __builtin_amdgcn_s_setprio(1);
          #pragma unroll
          for (int nt = 0; nt < 4; ++nt) {
            f32x4 z = {};
            sv[nt] = MFMA16(kf[nt][0], qa[qt][0], z);
            sv[nt] = MFMA16(kf[nt][1], qa[qt][1], sv[nt]);
          }
          __builtin_amdgcn_s_setprio(0);
          if (cb < base + 16 || cb + 63 > base + 512) {
            #pragma unroll
            for (int nt = 0; nt < 4; ++nt)
              #pragma unroll
              for (int r = 0; r < 4; ++r) {
                const int t1 = cb + nt * 16 + g * 4 + r - base;
                if (t1 < li || t1 > 512 + li) sv[nt][r] = -3e38f;
              }
          }
          unsigned int pw[4][2];
          #pragma unroll
          for (int nt = 0; nt < 4; ++nt) {
            float2 ab; ab.x = fexp2(sv[nt][0]); ab.y = fexp2(sv[nt][1]);
            float2 cd; cd.x = fexp2(sv[nt][2]); cd.y = fexp2(sv[nt][3]);
            union { __hip_bfloat162 h2; unsigned int u; } u0, u1;
            u0.h2 = __float22bfloat162_rn(ab);
            u1.h2 = __float22bfloat162_rn(cd);
            pw[nt][0] = u0.u;
            pw[nt][1] = u1.u;
          }
          short8 pbf[2];
          #pragma unroll
          for (int kst = 0; kst < 2; ++kst) {
            unsigned int A0 = pw[2 * kst][0], B0 = pw[2 * kst + 1][0];
            unsigned int A1 = pw[2 * kst][1], B1 = pw[2 * kst + 1][1];
            p32swap(A0, B0);
            p32swap(A1, B1);
            p16swap(A0, B0);
            p16swap(A1, B1);
            union { unsigned int u[4]; short8 s8; } pb_;
            pb_.u[0] = A0;
            pb_.u[1] = A1;
            pb_.u[2] = B0;
            pb_.u[3] = B1;
            pbf[kst] = pb_.s8;
          }
          __builtin_amdgcn_s_setprio(1);
          lac[qt] = MFMA16(vone, pbf[0], lac[qt]);
          lac[qt] = MFMA16(vone, pbf[1], lac[qt]);
          #pragma unroll
          for (int dt = 0; dt < 4; ++dt) {
            o[qt][dt] = MFMA16(vf[dt][0], pbf[0], o[qt][dt]);
            o[qt][dt] = MFMA16(vf[dt][1], pbf[1], o[qt][dt]);
          }
          __builtin_amdgcn_s_setprio(0);
        }
      }
    }
    RAW_BAR();
    pb ^= 1;
  }

  #pragma unroll
  for (int qt = 0; qt < 2; ++qt) {
    const float inv = 1.0f / lac[qt][0];
    const int t_ = qs + w * 32 + qt * 16 + li;
    #pragma unroll
    for (int dt = 0; dt < 4; ++dt) {
      ushort4 u;
      u.x = f2bf(o[qt][dt][0] * inv); u.y = f2bf(o[qt][dt][1] * inv);
      u.z = f2bf(o[qt][dt][2] * inv); u.w = f2bf(o[qt][dt][3] * inv);
      *(ushort4*)&O[((size_t)(b * 4096 + t_) << 10) + h * 64 + dt * 16 + g * 4] = u;
    }
  }
}

extern "C" void kernel_launch(void* const* d_in, const int* in_sizes, int n_in,
                              void* d_out, int out_size, void* d_ws, size_t ws_size,
                              hipStream_t stream) {
  const float* q_in = (const float*)d_in[0];
  const float* k_in = (const float*)d_in[1];
  const float* v_in = (const float*)d_in[2];
  const float* wq = (const float*)d_in[3];
  const float* bq = (const float*)d_in[4];
  const float* wk = (const float*)d_in[5];
  const float* bk = (const float*)d_in[6];
  const float* wv = (const float*)d_in[7];
  const float* bv = (const float*)d_in[8];
  const float* wo = (const float*)d_in[9];
  const float* bo = (const float*)d_in[10];

  unsigned short* Qw = (unsigned short*)d_ws;   // [2*16][4096][64] bf16 (pre-scaled)
  unsigned short* Kw = Qw + (size_t)8388608;    // [2*16][4096][64]
  unsigned short* Vw = Kw + (size_t)8388608;    // [2*16][64][4096]
  unsigned short* Tb = Vw + (size_t)8388608;    // q-staging, then attn out
  unsigned short* Wb = Tb + (size_t)8388608;    // weights bf16 [4][1024][1024]
  // k/v bf16 staging in d_out (16M shorts), overwritten by out_gemm.
  unsigned short* Kc = (unsigned short*)d_out;
  unsigned short* Vc = Kc + (size_t)8388608;

  dim3 bb(256), bg(512);
  cvt_all<<<14336, bb, 0, stream>>>(q_in, k_in, v_in, wq, wk, wv, wo,
                                    Tb, Kc, Vc, Wb);
  qkv_gemm<<<dim3(64, 8, 3), bg, 0, stream>>>(Tb, Kc, Vc, Wb, bq, bk, bv,
                                              Qw, Kw, Vw);
  swa_attn<<<512, bg, 0, stream>>>(Qw, Kw, Vw, Tb);
  out_gemm<<<dim3(64, 8), bg, 0, stream>>>(Tb, Wb + (3u << 20), bo,
                                           (float*)d_out);
}

// Round 18
// 148.138 us; speedup vs baseline: 1.0268x; 1.0123x over previous
//
#include <hip/hip_runtime.h>
#include <hip/hip_bf16.h>

typedef __attribute__((ext_vector_type(8))) short short8;
typedef __attribute__((ext_vector_type(4))) float f32x4;

__device__ __forceinline__ unsigned short f2bf(float f) {
  union { float f; unsigned int u; } x; x.f = f;
  unsigned int r = x.u + 0x7fffu + ((x.u >> 16) & 1u);
  return (unsigned short)(r >> 16);
}

// Raw hardware exp2 (single v_exp_f32) — round-11 proven (+9.6 us on attn).
__device__ __forceinline__ float fexp2(float x) {
#if __has_builtin(__builtin_amdgcn_exp2f)
  return __builtin_amdgcn_exp2f(x);
#else
  float r;
  asm("v_exp_f32 %0, %1" : "=v"(r) : "v"(x));
  return r;
#endif
}

#define MFMA16(a, b, c) __builtin_amdgcn_mfma_f32_16x16x32_bf16((a), (b), (c), 0, 0, 0)

__device__ __forceinline__ void gload_lds16(const void* g, void* l) {
  __builtin_amdgcn_global_load_lds((const __attribute__((address_space(1))) void*)g,
                                   (__attribute__((address_space(3))) void*)l, 16, 0, 0);
}

#define WAIT_VM(n) asm volatile("s_waitcnt vmcnt(" #n ")" ::: "memory")
#define RAW_BAR() asm volatile("s_barrier" ::: "memory")

// D,S distinct-value pair swaps (operands must hold DIFFERENT values so the
// register allocator cannot coalesce them — round-9 lesson).
__device__ __forceinline__ void p32swap(unsigned int& a, unsigned int& b) {
  asm volatile("v_permlane32_swap_b32 %0, %1" : "+v"(a), "+v"(b));
}
__device__ __forceinline__ void p16swap(unsigned int& a, unsigned int& b) {
  asm volatile("v_permlane16_swap_b32 %0, %1" : "+v"(a), "+v"(b));
}

// 0.125 (HEAD_DIM^-0.5) * log2(e): folded so attention can use exp2 directly.
#define QSCALE 0.1803368801111244f

// Fused f32->bf16 conversion for q,k,v and the four weights in ONE launch.
__global__ __launch_bounds__(256) void cvt_all(
    const float* __restrict__ q, const float* __restrict__ k,
    const float* __restrict__ v, const float* __restrict__ w0,
    const float* __restrict__ w1, const float* __restrict__ w2,
    const float* __restrict__ w3, unsigned short* __restrict__ Tb,
    unsigned short* __restrict__ Kc, unsigned short* __restrict__ Vc,
    unsigned short* __restrict__ Wb) {
  const int lin = blockIdx.x;
  const float* src;
  unsigned short* dst;
  int i0;
  if (lin < 4096)        { src = q;  dst = Tb;                i0 = lin; }
  else if (lin < 8192)   { src = k;  dst = Kc;                i0 = lin - 4096; }
  else if (lin < 12288)  { src = v;  dst = Vc;                i0 = lin - 8192; }
  else if (lin < 12800)  { src = w0; dst = Wb;                i0 = lin - 12288; }
  else if (lin < 13312)  { src = w1; dst = Wb + (1u << 20);   i0 = lin - 12800; }
  else if (lin < 13824)  { src = w2; dst = Wb + (2u << 20);   i0 = lin - 13312; }
  else                   { src = w3; dst = Wb + (3u << 20);   i0 = lin - 13824; }
  const size_t i = (size_t)i0 * 256 + threadIdx.x;
  const float4* p = (const float4*)src + 2 * i;
  float4 a = p[0], b = p[1];
  ushort4 lo, hi;
  lo.x = f2bf(a.x); lo.y = f2bf(a.y); lo.z = f2bf(a.z); lo.w = f2bf(a.w);
  hi.x = f2bf(b.x); hi.y = f2bf(b.y); hi.z = f2bf(b.z); hi.w = f2bf(b.w);
  ((ushort4*)dst)[2 * i] = lo;
  ((ushort4*)dst)[2 * i + 1] = hi;
}

// Shared GEMM core: C[m,n] = sum_k A[m,k]*W[n,k]; 128x128 tile, 8 waves,
// dbuf 2-phase counted-vmcnt, LDS XOR-swizzled, grid.x = bm (XCD = bm%8).
template <bool SWAP>
__device__ __forceinline__ void gemm_core(const unsigned short* __restrict__ A,
                                          const unsigned short* __restrict__ W,
                                          unsigned short (*As)[128 * 64],
                                          unsigned short (*Bs)[128 * 64],
                                          int bm, int bn, f32x4 (&acc)[2][4]) {
  const int tid = threadIdx.x, lane = tid & 63, wid = tid >> 6;
  const int g = lane >> 4, li = lane & 15;
  const int wr = wid >> 1, wc = wid & 1;
  const int trow = tid >> 3;
  const int js = (tid & 7) ^ (trow & 7);

  auto stage = [&](int kt, int pb) {
    const int k0 = kt << 6;
    #pragma unroll
    for (int r = 0; r < 2; ++r) {
      const int row = r * 64 + trow;
      gload_lds16(A + (size_t)(bm * 128 + row) * 1024 + k0 + js * 8,
                  &As[pb][(r * 64 + wid * 8) * 64]);
      gload_lds16(W + (size_t)(bn * 128 + row) * 1024 + k0 + js * 8,
                  &Bs[pb][(r * 64 + wid * 8) * 64]);
    }
  };

  stage(0, 0);
  int p = 0;
  for (int kt = 0; kt < 16; ++kt) {
    if (kt < 15) {
      stage(kt + 1, p ^ 1);
      WAIT_VM(4);
    } else {
      WAIT_VM(0);
    }
    RAW_BAR();
    #pragma unroll
    for (int kst = 0; kst < 2; ++kst) {
      short8 a[2], b[4];
      #pragma unroll
      for (int mi = 0; mi < 2; ++mi) {
        const int row = wr * 32 + mi * 16 + li;
        a[mi] = *(const short8*)((const char*)&As[p][0] + row * 128 +
                                 (((kst * 4 + g) ^ (li & 7)) << 4));
      }
      #pragma unroll
      for (int ni = 0; ni < 4; ++ni) {
        const int row = wc * 64 + ni * 16 + li;
        b[ni] = *(const short8*)((const char*)&Bs[p][0] + row * 128 +
                                 (((kst * 4 + g) ^ (li & 7)) << 4));
      }
      __builtin_amdgcn_s_setprio(1);
      #pragma unroll
      for (int mi = 0; mi < 2; ++mi)
        #pragma unroll
        for (int ni = 0; ni < 4; ++ni) {
          if constexpr (SWAP)
            acc[mi][ni] = MFMA16(b[ni], a[mi], acc[mi][ni]);
          else
            acc[mi][ni] = MFMA16(a[mi], b[ni], acc[mi][ni]);
        }
      __builtin_amdgcn_s_setprio(0);
    }
    RAW_BAR();
    p ^= 1;
  }
}

// Fused Q/K/V projection: grid (64 bm, 8 bn, 3 z). One launch (round-15).
__global__ __launch_bounds__(512) void qkv_gemm(
    const unsigned short* __restrict__ Aq, const unsigned short* __restrict__ Ak,
    const unsigned short* __restrict__ Av, const unsigned short* __restrict__ Wb,
    const float* __restrict__ bq, const float* __restrict__ bk,
    const float* __restrict__ bv, unsigned short* __restrict__ Qw,
    unsigned short* __restrict__ Kw, unsigned short* __restrict__ Vw) {
  __shared__ unsigned short As[2][128 * 64];
  __shared__ unsigned short Bs[2][128 * 64];
  const int z = blockIdx.z;
  const int bm = blockIdx.x, bn = blockIdx.y;
  const unsigned short* A = (z == 0) ? Aq : (z == 1) ? Ak : Av;
  const unsigned short* W = Wb + ((size_t)z << 20);
  const float* bias = (z == 0) ? bq : (z == 1) ? bk : bv;
  unsigned short* outp = (z == 0) ? Qw : (z == 1) ? Kw : Vw;

  const int tid = threadIdx.x, lane = tid & 63, wid = tid >> 6;
  const int g = lane >> 4, li = lane & 15;
  const int wr = wid >> 1, wc = wid & 1;

  f32x4 acc[2][4] = {};
  if (z == 2)
    gemm_core<true>(A, W, As, Bs, bm, bn, acc);
  else
    gemm_core<false>(A, W, As, Bs, bm, bn, acc);

  if (z == 2) {
    #pragma unroll
    for (int mi = 0; mi < 2; ++mi) {
      const int mm = bm * 128 + wr * 32 + mi * 16 + li;
      const int b_ = mm >> 12, t_ = mm & 4095;
      #pragma unroll
      for (int ni = 0; ni < 4; ++ni)
        #pragma unroll
        for (int r = 0; r < 4; ++r) {
          const int nn = bn * 128 + wc * 64 + ni * 16 + g * 4 + r;
          const int h_ = nn >> 6, d_ = nn & 63;
          float v = acc[mi][ni][r] + bias[nn];
          outp[(((size_t)(b_ * 16 + h_) * 64 + d_) << 12) + t_] = f2bf(v);
        }
    }
  } else {
    const float scale = (z == 0) ? QSCALE : 1.0f;
    #pragma unroll
    for (int mi = 0; mi < 2; ++mi)
      #pragma unroll
      for (int ni = 0; ni < 4; ++ni) {
        const int nn = bn * 128 + wc * 64 + ni * 16 + li;
        const float bv_ = bias[nn];
        #pragma unroll
        for (int r = 0; r < 4; ++r) {
          const int mm = bm * 128 + wr * 32 + mi * 16 + g * 4 + r;
          const float v = (acc[mi][ni][r] + bv_) * scale;
          const int b_ = mm >> 12, t_ = mm & 4095, h_ = nn >> 6, d_ = nn & 63;
          outp[(((size_t)(b_ * 16 + h_) * 4096 + t_) << 6) + d_] = f2bf(v);
        }
      }
  }
}

// Output projection (f32 out + bias).
__global__ __launch_bounds__(512) void out_gemm(const unsigned short* __restrict__ A,
                                                const unsigned short* __restrict__ W,
                                                const float* __restrict__ bias,
                                                float* __restrict__ outp) {
  __shared__ unsigned short As[2][128 * 64];
  __shared__ unsigned short Bs[2][128 * 64];
  const int bm = blockIdx.x, bn = blockIdx.y;
  const int tid = threadIdx.x, lane = tid & 63, wid = tid >> 6;
  const int g = lane >> 4, li = lane & 15;
  const int wr = wid >> 1, wc = wid & 1;
  f32x4 acc[2][4] = {};
  gemm_core<false>(A, W, As, Bs, bm, bn, acc);
  #pragma unroll
  for (int mi = 0; mi < 2; ++mi)
    #pragma unroll
    for (int ni = 0; ni < 4; ++ni) {
      const int nn = bn * 128 + wc * 64 + ni * 16 + li;
      const float bv_ = bias[nn];
      #pragma unroll
      for (int r = 0; r < 4; ++r) {
        const int mm = bm * 128 + wr * 32 + mi * 16 + g * 4 + r;
        outp[(size_t)mm * 1024 + nn] = acc[mi][ni][r] + bv_;
      }
    }
}

// Sliding-window attention, 8-wave Q256 + pair staging (r17) + cross-qt ILP
// (r18): both qt's QK MFMAs batched up front; then SM0->PV0->SM1->PV1 so
// PV(qt0)'s MFMA execution overlaps SM(qt1)'s VALU/trans (in-order issue,
// separate pipes). Per-qt `continue` removed (masked lanes -> exp2 = 0 ->
// zero contribution, provably safe) to keep the region branch-free.
__global__ __launch_bounds__(512) void swa_attn(const unsigned short* __restrict__ Q,
                                                const unsigned short* __restrict__ K,
                                                const unsigned short* __restrict__ V,
                                                unsigned short* __restrict__ O) {
  __shared__ unsigned short Kb[2][8192];   // pair: [128 keys][64 d], swizzled
  __shared__ unsigned short Vb[2][8192];   // pair: 2x [64 d][64 keys], swizzled
  const int tid = threadIdx.x, lane = tid & 63, w = tid >> 6;
  const int g = lane >> 4, li = lane & 15;
  const int lin = blockIdx.x;
  const int xcd = lin & 7;
  const int rest = lin >> 3;        // [0,64)
  const int qoff = rest & 7;
  const int grp = rest >> 3;
  const int G = xcd * 8 + grp;
  const int hb = G & 31;
  const int qb = (G >> 5) * 8 + qoff;  // [0,16)
  const int qs = qb << 8;
  const int h = hb & 15, b = hb >> 4;
  const int bh = b * 16 + h;
  const unsigned short* Qh = Q + ((size_t)bh << 18);
  const unsigned short* Kh = K + ((size_t)bh << 18);
  const unsigned short* Vh = V + ((size_t)bh << 18);

  short8 qa[2][2];
  #pragma unroll
  for (int qt = 0; qt < 2; ++qt)
    #pragma unroll
    for (int kst = 0; kst < 2; ++kst)
      qa[qt][kst] =
          *(const short8*)&Qh[((size_t)(qs + w * 32 + qt * 16 + li) << 6) + kst * 32 + g * 8];

  const short8 vone = {0x3F80, 0x3F80, 0x3F80, 0x3F80, 0x3F80, 0x3F80, 0x3F80, 0x3F80};
  f32x4 o[2][4] = {};
  f32x4 lac[2] = {};
  const int c0 = (qs >= 512) ? 0 : ((512 - qs) >> 6);
  const int p0 = c0 >> 1;

  const int srow_hi = lane >> 3;
  const int sj = lane & 7;

  auto stage = [&](int pi, int pb) {
    const int ks0 = qs - 512 + (pi << 7);
    #pragma unroll
    for (int ss = 0; ss < 2; ++ss) {
      const int row = w * 8 + srow_hi;
      const int jsw = sj ^ (row & 7);
      gload_lds16(Kh + (((size_t)(ks0 + ss * 64 + row)) << 6) + jsw * 8,
                  &Kb[pb][ss * 4096 + w * 512]);
      gload_lds16(Vh + (((size_t)row) << 12) + ks0 + ss * 64 + jsw * 8,
                  &Vb[pb][ss * 4096 + w * 512]);
    }
  };

  int pb = 0;
  stage(p0, 0);

  for (int pi = p0; pi <= 5; ++pi) {
    if (pi < 5) {
      stage(pi + 1, pb ^ 1);
      WAIT_VM(4);
    } else {
      WAIT_VM(0);
    }
    RAW_BAR();
    #pragma unroll
    for (int ss = 0; ss < 2; ++ss) {
      const int c = 2 * pi + ss;
      const int cb = c << 6;
      const bool anyq = (cb + 63 >= w * 32) && (cb <= w * 32 + 543);
      if (anyq) {
        // K fragments, then BOTH qt's QK batched (8+8 independent MFMAs)
        short8 kf[4][2];
        #pragma unroll
        for (int nt = 0; nt < 4; ++nt) {
          const int row = nt * 16 + li, rx = li & 7;
          #pragma unroll
          for (int kst = 0; kst < 2; ++kst) {
            const int byt = ss * 8192 + row * 128 + (((kst * 4 + g) ^ rx) << 4);
            kf[nt][kst] = *(const short8*)((const char*)&Kb[pb][0] + byt);
          }
        }
        f32x4 sv[2][4];
        __builtin_amdgcn_s_setprio(1);
        #pragma unroll
        for (int qt = 0; qt < 2; ++qt)
          #pragma unroll
          for (int nt = 0; nt < 4; ++nt) {
            f32x4 z = {};
            sv[qt][nt] = MFMA16(kf[nt][0], qa[qt][0], z);
            sv[qt][nt] = MFMA16(kf[nt][1], qa[qt][1], sv[qt][nt]);
          }
        __builtin_amdgcn_s_setprio(0);
        // masks (covers fully-out-of-range qt too: all lanes -> -inf -> 0)
        #pragma unroll
        for (int qt = 0; qt < 2; ++qt) {
          const int base = w * 32 + qt * 16;
          if (cb < base + 16 || cb + 63 > base + 512) {
            #pragma unroll
            for (int nt = 0; nt < 4; ++nt)
              #pragma unroll
              for (int r = 0; r < 4; ++r) {
                const int t1 = cb + nt * 16 + g * 4 + r - base;
                if (t1 < li || t1 > 512 + li) sv[qt][nt][r] = -3e38f;
              }
          }
        }
        // V fragments (ds_read latency hides under SM0)
        short8 vf[4][2];
        #pragma unroll
        for (int dt = 0; dt < 4; ++dt) {
          const int row = dt * 16 + li, rx = li & 7;
          #pragma unroll
          for (int kst = 0; kst < 2; ++kst) {
            const int byt = ss * 8192 + row * 128 + (((kst * 4 + g) ^ rx) << 4);
            vf[dt][kst] = *(const short8*)((const char*)&Vb[pb][0] + byt);
          }
        }
        // SM0 -> PV0 -> SM1 -> PV1: PV0 MFMA execution overlaps SM1 VALU.
        #pragma unroll
        for (int qt = 0; qt < 2; ++qt) {
          unsigned int pw[4][2];
          #pragma unroll
          for (int nt = 0; nt < 4; ++nt) {
            float2 ab; ab.x = fexp2(sv[qt][nt][0]); ab.y = fexp2(sv[qt][nt][1]);
            float2 cd; cd.x = fexp2(sv[qt][nt][2]); cd.y = fexp2(sv[qt][nt][3]);
            union { __hip_bfloat162 h2; unsigned int u; } u0, u1;
            u0.h2 = __float22bfloat162_rn(ab);
            u1.h2 = __float22bfloat162_rn(cd);
            pw[nt][0] = u0.u;
            pw[nt][1] = u1.u;
          }
          short8 pbf[2];
          #pragma unroll
          for (int kst = 0; kst < 2; ++kst) {
            unsigned int A0 = pw[2 * kst][0], B0 = pw[2 * kst + 1][0];
            unsigned int A1 = pw[2 * kst][1], B1 = pw[2 * kst + 1][1];
            p32swap(A0, B0);
            p32swap(A1, B1);
            p16swap(A0, B0);
            p16swap(A1, B1);
            union { unsigned int u[4]; short8 s8; } pb_;
            pb_.u[0] = A0;
            pb_.u[1] = A1;
            pb_.u[2] = B0;
            pb_.u[3] = B1;
            pbf[kst] = pb_.s8;
          }
          __builtin_amdgcn_s_setprio(1);
          lac[qt] = MFMA16(vone, pbf[0], lac[qt]);
          lac[qt] = MFMA16(vone, pbf[1], lac[qt]);
          #pragma unroll
          for (int dt = 0; dt < 4; ++dt) {
            o[qt][dt] = MFMA16(vf[dt][0], pbf[0], o[qt][dt]);
            o[qt][dt] = MFMA16(vf[dt][1], pbf[1], o[qt][dt]);
          }
          __builtin_amdgcn_s_setprio(0);
        }
      }
    }
    RAW_BAR();
    pb ^= 1;
  }

  #pragma unroll
  for (int qt = 0; qt < 2; ++qt) {
    const float inv = 1.0f / lac[qt][0];
    const int t_ = qs + w * 32 + qt * 16 + li;
    #pragma unroll
    for (int dt = 0; dt < 4; ++dt) {
      ushort4 u;
      u.x = f2bf(o[qt][dt][0] * inv); u.y = f2bf(o[qt][dt][1] * inv);
      u.z = f2bf(o[qt][dt][2] * inv); u.w = f2bf(o[qt][dt][3] * inv);
      *(ushort4*)&O[((size_t)(b * 4096 + t_) << 10) + h * 64 + dt * 16 + g * 4] = u;
    }
  }
}

extern "C" void kernel_launch(void* const* d_in, const int* in_sizes, int n_in,
                              void* d_out, int out_size, void* d_ws, size_t ws_size,
                              hipStream_t stream) {
  const float* q_in = (const float*)d_in[0];
  const float* k_in = (const float*)d_in[1];
  const float* v_in = (const float*)d_in[2];
  const float* wq = (const float*)d_in[3];
  const float* bq = (const float*)d_in[4];
  const float* wk = (const float*)d_in[5];
  const float* bk = (const float*)d_in[6];
  const float* wv = (const float*)d_in[7];
  const float* bv = (const float*)d_in[8];
  const float* wo = (const float*)d_in[9];
  const float* bo = (const float*)d_in[10];

  unsigned short* Qw = (unsigned short*)d_ws;   // [2*16][4096][64] bf16 (pre-scaled)
  unsigned short* Kw = Qw + (size_t)8388608;    // [2*16][4096][64]
  unsigned short* Vw = Kw + (size_t)8388608;    // [2*16][64][4096]
  unsigned short* Tb = Vw + (size_t)8388608;    // q-staging, then attn out
  unsigned short* Wb = Tb + (size_t)8388608;    // weights bf16 [4][1024][1024]
  // k/v bf16 staging in d_out (16M shorts), overwritten by out_gemm.
  unsigned short* Kc = (unsigned short*)d_out;
  unsigned short* Vc = Kc + (size_t)8388608;

  dim3 bb(256), bg(512);
  cvt_all<<<14336, bb, 0, stream>>>(q_in, k_in, v_in, wq, wk, wv, wo,
                                    Tb, Kc, Vc, Wb);
  qkv_gemm<<<dim3(64, 8, 3), bg, 0, stream>>>(Tb, Kc, Vc, Wb, bq, bk, bv,
                                              Qw, Kw, Vw);
  swa_attn<<<512, bg, 0, stream>>>(Qw, Kw, Vw, Tb);
  out_gemm<<<dim3(64, 8), bg, 0, stream>>>(Tb, Wb + (3u << 20), bo,
                                           (float*)d_out);
}